// Round 1
// baseline (162.721 us; speedup 1.0000x reference)
//
#include <hip/hip_runtime.h>
#include <hip/hip_bf16.h>
#include <stdint.h>

// Shapes (fixed by the problem)
#define B_ROWS 16384
#define VDIM   16
#define SDIM   64
#define HDIM   512
#define KDIM   1024   // V*S
#define KP     1056   // KDIM + 16 bias cols + 16 zero pad (multiple of 32)
#define ASTR   1064   // LDS A' row stride in elems (1056 + 8 pad)
#define MROWS  32     // rows per block (was 64) -> LDS 78,848 B -> 2 blocks/CU
// LDS: As 32*1064*2 = 68096 | plog 8*16*17*4 = 8704 | wlds 32*16*4 = 2048
#define PLOG_OFF 68096
#define WLDS_OFF (68096 + 8704)
#define K2_LDS   (68096 + 8704 + 2048)   // 78848 B

using bf16x8 = __attribute__((ext_vector_type(8))) __bf16;
using u16x8  = __attribute__((ext_vector_type(8))) unsigned short;
using f32x4  = __attribute__((ext_vector_type(4))) float;

__device__ __forceinline__ unsigned short f2bf(float f) {
  unsigned int u = __builtin_bit_cast(unsigned int, f);
  u = (u + 0x7FFFu + ((u >> 16) & 1u)) >> 16;   // RNE
  return (unsigned short)u;
}
__device__ __forceinline__ float bf2f(unsigned short s) {
  return __builtin_bit_cast(float, (unsigned int)s << 16);
}

// ---------------------------------------------------------------------------
// K0 (merged):
//   blocks [0,66):   Bt = [W_cat ; bias ; 0]^T bf16 [HDIM][KP] via LDS-transpose
//                    tiles (32 k x 256 n). Coalesced reads, 64B-contiguous writes.
//   blocks [66,322): WcombT rows; block 322: bcomb.
__global__ __launch_bounds__(256) void k0_prep(
    const float* __restrict__ W, const float* __restrict__ bias,
    const float* __restrict__ Wsel, const float* __restrict__ bsel,
    unsigned short* __restrict__ Bt, unsigned short* __restrict__ WcombT,
    float* __restrict__ bcomb) {
  __shared__ float bm[HDIM];
  __shared__ float part[16][17];
  __shared__ unsigned short tile[32][264];
  const int t = threadIdx.x;
  if (blockIdx.x < 66) {
    const int k0 = (blockIdx.x >> 1) * 32;          // 0..1024 step 32
    const int n  = ((blockIdx.x & 1) << 8) + t;     // 0..511
    #pragma unroll 8
    for (int kk = 0; kk < 32; ++kk) {
      const int k = k0 + kk;
      float val;
      if (k < KDIM)            val = W[(size_t)k * HDIM + n];
      else if (k < KDIM + 16)  val = bias[(size_t)(k - KDIM) * HDIM + n];
      else                     val = 0.f;
      tile[kk][t] = f2bf(val);
    }
    __syncthreads();
    // transposed write: thread owns column n, 32 consecutive k = 64 B
    unsigned short* dst = Bt + (size_t)n * KP + k0;
    #pragma unroll
    for (int seg = 0; seg < 4; ++seg) {
      unsigned short o[8];
      #pragma unroll
      for (int jj = 0; jj < 8; ++jj) o[jj] = tile[seg * 8 + jj][t];
      *(u16x8*)(dst + seg * 8) = *(const u16x8*)o;
    }
    return;
  }
  const int bid = blockIdx.x - 66;     // 0..256
  if (bid < 256) {
    const int wave = t >> 6, lane = t & 63;
    const int k = bid * 4 + wave;
    const float* wr = W + (size_t)k * HDIM;
    float s[16];
    #pragma unroll
    for (int v = 0; v < 16; ++v) s[v] = 0.f;
    #pragma unroll
    for (int j = 0; j < 8; ++j) {
      const int h = lane + 64 * j;
      const float a = wr[h];
      const float4* wl = (const float4*)(Wsel + h * 16);
      const float4 q0 = wl[0], q1 = wl[1], q2 = wl[2], q3 = wl[3];
      s[0]  = fmaf(a, q0.x, s[0]);  s[1]  = fmaf(a, q0.y, s[1]);
      s[2]  = fmaf(a, q0.z, s[2]);  s[3]  = fmaf(a, q0.w, s[3]);
      s[4]  = fmaf(a, q1.x, s[4]);  s[5]  = fmaf(a, q1.y, s[5]);
      s[6]  = fmaf(a, q1.z, s[6]);  s[7]  = fmaf(a, q1.w, s[7]);
      s[8]  = fmaf(a, q2.x, s[8]);  s[9]  = fmaf(a, q2.y, s[9]);
      s[10] = fmaf(a, q2.z, s[10]); s[11] = fmaf(a, q2.w, s[11]);
      s[12] = fmaf(a, q3.x, s[12]); s[13] = fmaf(a, q3.y, s[13]);
      s[14] = fmaf(a, q3.z, s[14]); s[15] = fmaf(a, q3.w, s[15]);
    }
    #pragma unroll
    for (int off = 32; off > 0; off >>= 1) {
      #pragma unroll
      for (int v = 0; v < 16; ++v) s[v] += __shfl_xor(s[v], off, 64);
    }
    float mine = 0.f;
    #pragma unroll
    for (int v = 0; v < 16; ++v) mine = (lane == v) ? s[v] : mine;
    if (lane < 16) WcombT[lane * KDIM + k] = f2bf(mine * (1.f / 16.f));
  } else {
    for (int h = t; h < HDIM; h += 256) {
      float s = 0.f;
      #pragma unroll
      for (int v = 0; v < VDIM; ++v) s += bias[v * HDIM + h];
      bm[h] = s * (1.f / 16.f);
    }
    __syncthreads();
    int v = t & 15, sl = t >> 4;
    float s = 0.f;
    for (int h = sl * 32; h < sl * 32 + 32; ++h) s = fmaf(bm[h], Wsel[h * VDIM + v], s);
    part[sl][v] = s;
    __syncthreads();
    if (t < 16) {
      float s2 = bsel[t];
      #pragma unroll
      for (int i = 0; i < 16; ++i) s2 += part[i][t];
      bcomb[t] = s2;
    }
  }
}

// ---------------------------------------------------------------------------
// K2f: FULLY FUSED gate+scale+GEMM. Block M32 x N512, grid 512 = 2 blocks/CU.
// Same 5-phase structure as before but half the tile so two blocks co-reside
// per CU and phase-shift against each other (stage/HBM overlaps K-loop/L2+MFMA).
// x loads + C stores are nontemporal: keep L2 for Bt/WcombT.
__global__ __launch_bounds__(512, 4) void k2f_fused(
    const float* __restrict__ x, const unsigned short* __restrict__ WcombT,
    const float* __restrict__ bcomb, const unsigned short* __restrict__ Bt,
    float* __restrict__ C) {
  extern __shared__ unsigned short As[];          // [32][ASTR] bf16
  float* plog = (float*)((char*)As + PLOG_OFF);   // [8][16][17]
  float* wlds = (float*)((char*)As + WLDS_OFF);   // [32][16]

  const int t = threadIdx.x;
  const int rowb = blockIdx.x * MROWS;
  const int wave = t >> 6, lane = t & 63;
  const int mlane = lane & 15, quad = lane >> 4;

  // ---- Phase 1: stage bf16(x) unscaled; keep register copy.
  const int srow = t >> 4;              // 0..31
  const int sc = (t & 15) * 8;          // 0..120 ; covers k = sc + i*128
  u16x8 xreg[8];
  {
    const float* xr = x + (size_t)(rowb + srow) * KDIM + sc;
    unsigned short* aw = As + srow * ASTR + sc;
    #pragma unroll
    for (int i = 0; i < 8; ++i) {
      const f32x4 a0 = __builtin_nontemporal_load((const f32x4*)(xr + i * 128));
      const f32x4 a1 = __builtin_nontemporal_load((const f32x4*)(xr + i * 128 + 4));
      u16x8 u;
      u[0] = f2bf(a0[0]); u[1] = f2bf(a0[1]); u[2] = f2bf(a0[2]); u[3] = f2bf(a0[3]);
      u[4] = f2bf(a1[0]); u[5] = f2bf(a1[1]); u[6] = f2bf(a1[2]); u[7] = f2bf(a1[3]);
      xreg[i] = u;
      *(u16x8*)(aw + i * 128) = u;
    }
  }
  __syncthreads();   // barrier 1: As(x) visible

  // ---- Phase 2: partial logits. wave w: kh = w>>1 (K-quarter), rg = w&1 (rows)
  {
    const int kh = wave >> 1, rg = wave & 1;
    const unsigned short* al = As + (rg * 16 + mlane) * ASTR + kh * 256 + quad * 8;
    const unsigned short* bl = WcombT + mlane * KDIM + kh * 256 + quad * 8;
    f32x4 acc = {0.f, 0.f, 0.f, 0.f};
    #pragma unroll
    for (int kt = 0; kt < 8; ++kt) {
      bf16x8 a = *(const bf16x8*)al; al += 32;
      bf16x8 b = *(const bf16x8*)bl; bl += 32;
      acc = __builtin_amdgcn_mfma_f32_16x16x32_bf16(a, b, acc, 0, 0, 0);
    }
    // C layout: col(v)=lane&15, row=quad*4+r
    float* pl = plog + ((size_t)((kh * 2 + rg) * 16 + quad * 4) * 17 + mlane);
    #pragma unroll
    for (int r = 0; r < 4; ++r) pl[r * 17] = acc[r];
  }
  __syncthreads();   // barrier 2: plog visible

  // ---- Phase 3: softmax on 32 threads (row = t)
  if (t < 32) {
    const int rg = t >> 4, rr = t & 15;
    float l[16];
    float mx = -1e30f;
    #pragma unroll
    for (int v = 0; v < 16; ++v) {
      float s = bcomb[v];
      #pragma unroll
      for (int kq = 0; kq < 4; ++kq)
        s += plog[((size_t)((kq * 2 + rg) * 16 + rr)) * 17 + v];
      l[v] = s;
      mx = fmaxf(mx, s);
    }
    float s = 0.f;
    #pragma unroll
    for (int v = 0; v < 16; ++v) { l[v] = __expf(l[v] - mx); s += l[v]; }
    const float inv = 1.f / s;
    float* wo = wlds + t * 16;
    #pragma unroll
    for (int v = 0; v < 16; ++v) wo[v] = l[v] * inv;
  }
  __syncthreads();   // barrier 3: wlds visible

  // ---- Phase 4: rescale A' from register copy; write bias tail
  {
    float wv[16];
    const f32x4* wq = (const f32x4*)(wlds + srow * 16);
    #pragma unroll
    for (int q = 0; q < 4; ++q) {
      const f32x4 f = wq[q];
      wv[4 * q + 0] = f[0]; wv[4 * q + 1] = f[1];
      wv[4 * q + 2] = f[2]; wv[4 * q + 3] = f[3];
    }
    const int vbase = (t & 15) >> 3;    // v = 2*i + vbase  (k = sc + 128*i)
    unsigned short* aw = As + srow * ASTR + sc;
    #pragma unroll
    for (int i = 0; i < 8; ++i) {
      const float w = wv[2 * i + vbase];
      const u16x8 a = xreg[i];
      u16x8 o;
      #pragma unroll
      for (int j = 0; j < 8; ++j) o[j] = f2bf(w * bf2f(a[j]));
      *(u16x8*)(aw + i * 128) = o;
    }
    if ((t & 15) < 4) {
      const int j8 = (t & 15) * 8;      // 0,8,16,24
      unsigned short o[8];
      #pragma unroll
      for (int jj = 0; jj < 8; ++jj)
        o[jj] = (j8 + jj < 16) ? f2bf(wv[j8 + jj]) : (unsigned short)0;
      *(u16x8*)(As + srow * ASTR + KDIM + j8) = *(const u16x8*)o;
    }
  }

  // ---- B pointers + 2-deep prefetch issued BEFORE the last barrier
  const int colb = wave * 64;
  const unsigned short* bp[4];
  #pragma unroll
  for (int j = 0; j < 4; ++j)
    bp[j] = Bt + (size_t)(colb + j * 16 + mlane) * KP + quad * 8;

  bf16x8 bv0[4], bv1[4];
  #pragma unroll
  for (int j = 0; j < 4; ++j) {
    bv0[j] = *(const bf16x8*)(bp[j]);
    bv1[j] = *(const bf16x8*)(bp[j] + 32);
    bp[j] += 64;
  }

  __syncthreads();   // barrier 4: A' final

  // ---- Phase 5: main GEMM K-loop (barrier-free), 2 row-tiles x 4 col-tiles
  const unsigned short* ap[2];
  #pragma unroll
  for (int i = 0; i < 2; ++i)
    ap[i] = As + (i * 16 + mlane) * ASTR + quad * 8;

  f32x4 acc[2][4];
  const f32x4 z = {0.f, 0.f, 0.f, 0.f};
  #pragma unroll
  for (int i = 0; i < 2; ++i)
    #pragma unroll
    for (int j = 0; j < 4; ++j) acc[i][j] = z;

  #pragma unroll 1
  for (int kt = 0; kt < 33; ++kt) {
    bf16x8 bnext[4];
    if (kt < 31) {
      #pragma unroll
      for (int j = 0; j < 4; ++j) { bnext[j] = *(const bf16x8*)bp[j]; bp[j] += 32; }
    }
    bf16x8 av[2];
    #pragma unroll
    for (int i = 0; i < 2; ++i) { av[i] = *(const bf16x8*)ap[i]; ap[i] += 32; }
    #pragma unroll
    for (int i = 0; i < 2; ++i)
      #pragma unroll
      for (int j = 0; j < 4; ++j)
        acc[i][j] = __builtin_amdgcn_mfma_f32_16x16x32_bf16(av[i], bv0[j], acc[i][j], 0, 0, 0);
    #pragma unroll
    for (int j = 0; j < 4; ++j) { bv0[j] = bv1[j]; bv1[j] = bnext[j]; }
  }

  // ---- epilogue: C/D layout col=lane&15, row=quad*4+reg  [m89/m91]
  #pragma unroll
  for (int i = 0; i < 2; ++i)
    #pragma unroll
    for (int j = 0; j < 4; ++j)
      #pragma unroll
      for (int r = 0; r < 4; ++r) {
        const size_t row = (size_t)rowb + i * 16 + quad * 4 + r;
        const int col = colb + j * 16 + mlane;
        __builtin_nontemporal_store(acc[i][j][r], &C[row * HDIM + col]);
      }
}

// ---------------------------------------------------------------------------
extern "C" void kernel_launch(void* const* d_in, const int* in_sizes, int n_in,
                              void* d_out, int out_size, void* d_ws, size_t ws_size,
                              hipStream_t stream) {
  const float* x    = (const float*)d_in[0];   // [B, V, S] = [16384][1024] flat
  const float* W    = (const float*)d_in[1];   // [V, S, H] = [1024][512] flat
  const float* bias = (const float*)d_in[2];   // [V, H]
  const float* Wsel = (const float*)d_in[3];   // [H, V]
  const float* bsel = (const float*)d_in[4];   // [V]
  float* out = (float*)d_out;                  // [B, H] fp32

  char* ws = (char*)d_ws;
  unsigned short* Bt     = (unsigned short*)(ws);            // 512*1056*2 = 1,081,344 B
  unsigned short* WcombT = (unsigned short*)(ws + 1081344);  // 16*1024*2  =    32,768 B
  float*          bcomb  = (float*)(ws + 1114112);           // 16*4 (padded to 256)

  static int lds_set = 0;
  if (!lds_set) {
    hipFuncSetAttribute((const void*)k2f_fused,
                        hipFuncAttributeMaxDynamicSharedMemorySize, K2_LDS);
    lds_set = 1;
  }

  k0_prep<<<323, 256, 0, stream>>>(W, bias, Wsel, bsel, Bt, WcombT, bcomb);
  k2f_fused<<<512, 512, K2_LDS, stream>>>(x, WcombT, bcomb, Bt, out);
}

// Round 2
// 161.085 us; speedup vs baseline: 1.0102x; 1.0102x over previous
//
#include <hip/hip_runtime.h>
#include <hip/hip_bf16.h>
#include <stdint.h>

// Shapes (fixed by the problem)
#define B_ROWS 16384
#define VDIM   16
#define SDIM   64
#define HDIM   512
#define KDIM   1024   // V*S
#define KP     1056   // KDIM + 16 bias cols + 16 zero pad

// ---- k1_gate LDS layout (M32 tile, same as proven R1 phases 1-3)
#define ASTR     1064                 // LDS x-row stride in u16 (1056+8 pad)
#define G_PLOG   68096                // 32*1064*2
#define G_LDS    (68096 + 8704)       // + plog [8][16][17] f32 = 76,800 B -> 2 blk/CU

// ---- k2_gemm LDS layout: double-buffered A-chunk [64][296] bf16
#define CSTR     296                  // 256 + 40 pad (stride words ≡ 20 mod 32, proven pattern)
#define BUFU16   (64 * CSTR)          // 18,944 u16 per buffer
#define GEMM_LDS (2 * BUFU16 * 2)     // 75,776 B

using bf16x8 = __attribute__((ext_vector_type(8))) __bf16;
using u16x8  = __attribute__((ext_vector_type(8))) unsigned short;
using u16x4  = __attribute__((ext_vector_type(4))) unsigned short;
using f32x4  = __attribute__((ext_vector_type(4))) float;

__device__ __forceinline__ unsigned short f2bf(float f) {
  unsigned int u = __builtin_bit_cast(unsigned int, f);
  u = (u + 0x7FFFu + ((u >> 16) & 1u)) >> 16;   // RNE
  return (unsigned short)u;
}
__device__ __forceinline__ float bf2f(unsigned short s) {
  return __builtin_bit_cast(float, (unsigned int)s << 16);
}

// ---------------------------------------------------------------------------
// K0 (merged):
//   blocks [0,66):   Bt = [W_cat ; bias ; 0]^T bf16 [HDIM][KP] via LDS-transpose
//   blocks [66,322): WcombT rows; block 322: bcomb.
__global__ __launch_bounds__(256) void k0_prep(
    const float* __restrict__ W, const float* __restrict__ bias,
    const float* __restrict__ Wsel, const float* __restrict__ bsel,
    unsigned short* __restrict__ Bt, unsigned short* __restrict__ WcombT,
    float* __restrict__ bcomb) {
  __shared__ float bm[HDIM];
  __shared__ float part[16][17];
  __shared__ unsigned short tile[32][264];
  const int t = threadIdx.x;
  if (blockIdx.x < 66) {
    const int k0 = (blockIdx.x >> 1) * 32;          // 0..1024 step 32
    const int n  = ((blockIdx.x & 1) << 8) + t;     // 0..511
    #pragma unroll 8
    for (int kk = 0; kk < 32; ++kk) {
      const int k = k0 + kk;
      float val;
      if (k < KDIM)            val = W[(size_t)k * HDIM + n];
      else if (k < KDIM + 16)  val = bias[(size_t)(k - KDIM) * HDIM + n];
      else                     val = 0.f;
      tile[kk][t] = f2bf(val);
    }
    __syncthreads();
    unsigned short* dst = Bt + (size_t)n * KP + k0;
    #pragma unroll
    for (int seg = 0; seg < 4; ++seg) {
      unsigned short o[8];
      #pragma unroll
      for (int jj = 0; jj < 8; ++jj) o[jj] = tile[seg * 8 + jj][t];
      *(u16x8*)(dst + seg * 8) = *(const u16x8*)o;
    }
    return;
  }
  const int bid = blockIdx.x - 66;     // 0..256
  if (bid < 256) {
    const int wave = t >> 6, lane = t & 63;
    const int k = bid * 4 + wave;
    const float* wr = W + (size_t)k * HDIM;
    float s[16];
    #pragma unroll
    for (int v = 0; v < 16; ++v) s[v] = 0.f;
    #pragma unroll
    for (int j = 0; j < 8; ++j) {
      const int h = lane + 64 * j;
      const float a = wr[h];
      const float4* wl = (const float4*)(Wsel + h * 16);
      const float4 q0 = wl[0], q1 = wl[1], q2 = wl[2], q3 = wl[3];
      s[0]  = fmaf(a, q0.x, s[0]);  s[1]  = fmaf(a, q0.y, s[1]);
      s[2]  = fmaf(a, q0.z, s[2]);  s[3]  = fmaf(a, q0.w, s[3]);
      s[4]  = fmaf(a, q1.x, s[4]);  s[5]  = fmaf(a, q1.y, s[5]);
      s[6]  = fmaf(a, q1.z, s[6]);  s[7]  = fmaf(a, q1.w, s[7]);
      s[8]  = fmaf(a, q2.x, s[8]);  s[9]  = fmaf(a, q2.y, s[9]);
      s[10] = fmaf(a, q2.z, s[10]); s[11] = fmaf(a, q2.w, s[11]);
      s[12] = fmaf(a, q3.x, s[12]); s[13] = fmaf(a, q3.y, s[13]);
      s[14] = fmaf(a, q3.z, s[14]); s[15] = fmaf(a, q3.w, s[15]);
    }
    #pragma unroll
    for (int off = 32; off > 0; off >>= 1) {
      #pragma unroll
      for (int v = 0; v < 16; ++v) s[v] += __shfl_xor(s[v], off, 64);
    }
    float mine = 0.f;
    #pragma unroll
    for (int v = 0; v < 16; ++v) mine = (lane == v) ? s[v] : mine;
    if (lane < 16) WcombT[lane * KDIM + k] = f2bf(mine * (1.f / 16.f));
  } else {
    for (int h = t; h < HDIM; h += 256) {
      float s = 0.f;
      #pragma unroll
      for (int v = 0; v < VDIM; ++v) s += bias[v * HDIM + h];
      bm[h] = s * (1.f / 16.f);
    }
    __syncthreads();
    int v = t & 15, sl = t >> 4;
    float s = 0.f;
    for (int h = sl * 32; h < sl * 32 + 32; ++h) s = fmaf(bm[h], Wsel[h * VDIM + v], s);
    part[sl][v] = s;
    __syncthreads();
    if (t < 16) {
      float s2 = bsel[t];
      #pragma unroll
      for (int i = 0; i < 16; ++i) s2 += part[i][t];
      bcomb[t] = s2;
    }
  }
}

// ---------------------------------------------------------------------------
// K1: gate only. M32 tile, grid 512, 2 blocks/CU. Stage bf16(x) -> LDS,
// logits via MFMA vs WcombT, softmax, write w[B][16] fp32. x loads CACHED
// (k2_gemm re-reads x from L3 right after).
__global__ __launch_bounds__(512, 4) void k1_gate(
    const float* __restrict__ x, const unsigned short* __restrict__ WcombT,
    const float* __restrict__ bcomb, float* __restrict__ wgate) {
  extern __shared__ unsigned short As[];          // [32][ASTR] bf16
  float* plog = (float*)((char*)As + G_PLOG);     // [8][16][17]

  const int t = threadIdx.x;
  const int rowb = blockIdx.x * 32;
  const int wave = t >> 6, lane = t & 63;
  const int mlane = lane & 15, quad = lane >> 4;

  // ---- Phase 1: stage bf16(x)
  {
    const int srow = t >> 4;            // 0..31
    const int sc = (t & 15) * 8;        // covers k = sc + i*128
    const float* xr = x + (size_t)(rowb + srow) * KDIM + sc;
    unsigned short* aw = As + srow * ASTR + sc;
    #pragma unroll
    for (int i = 0; i < 8; ++i) {
      const float4 a0 = *(const float4*)(xr + i * 128);
      const float4 a1 = *(const float4*)(xr + i * 128 + 4);
      u16x8 u;
      u[0] = f2bf(a0.x); u[1] = f2bf(a0.y); u[2] = f2bf(a0.z); u[3] = f2bf(a0.w);
      u[4] = f2bf(a1.x); u[5] = f2bf(a1.y); u[6] = f2bf(a1.z); u[7] = f2bf(a1.w);
      *(u16x8*)(aw + i * 128) = u;
    }
  }
  __syncthreads();

  // ---- Phase 2: partial logits. wave w: kh = w>>1 (K-quarter), rg = w&1
  {
    const int kh = wave >> 1, rg = wave & 1;
    const unsigned short* al = As + (rg * 16 + mlane) * ASTR + kh * 256 + quad * 8;
    const unsigned short* bl = WcombT + mlane * KDIM + kh * 256 + quad * 8;
    f32x4 acc = {0.f, 0.f, 0.f, 0.f};
    #pragma unroll
    for (int kt = 0; kt < 8; ++kt) {
      bf16x8 a = *(const bf16x8*)al; al += 32;
      bf16x8 b = *(const bf16x8*)bl; bl += 32;
      acc = __builtin_amdgcn_mfma_f32_16x16x32_bf16(a, b, acc, 0, 0, 0);
    }
    float* pl = plog + ((size_t)((kh * 2 + rg) * 16 + quad * 4) * 17 + mlane);
    #pragma unroll
    for (int r = 0; r < 4; ++r) pl[r * 17] = acc[r];
  }
  __syncthreads();

  // ---- Phase 3: softmax on 32 threads (row = t), write w to global
  if (t < 32) {
    const int rg = t >> 4, rr = t & 15;
    float l[16];
    float mx = -1e30f;
    #pragma unroll
    for (int v = 0; v < 16; ++v) {
      float s = bcomb[v];
      #pragma unroll
      for (int kq = 0; kq < 4; ++kq)
        s += plog[((size_t)((kq * 2 + rg) * 16 + rr)) * 17 + v];
      l[v] = s;
      mx = fmaxf(mx, s);
    }
    float s = 0.f;
    #pragma unroll
    for (int v = 0; v < 16; ++v) { l[v] = __expf(l[v] - mx); s += l[v]; }
    const float inv = 1.f / s;
    float* wo = wgate + (size_t)(rowb + t) * 16;
    #pragma unroll
    for (int q = 0; q < 4; ++q) {
      f32x4 o = {l[4*q] * inv, l[4*q+1] * inv, l[4*q+2] * inv, l[4*q+3] * inv};
      *(f32x4*)(wo + 4 * q) = o;
    }
  }
}

// ---------------------------------------------------------------------------
// K2: standard chunked double-buffered GEMM. M64 x N512, grid 256.
// A-chunk [64][256] bf16 staged per chunk: x fp32 (L3-hot) * w -> bf16 -> LDS.
// stage(c+1) overlaps MFMA(c); one barrier per chunk; B from L2 w/ 2-deep
// register prefetch (never drained mid-chunk except at barrier).
__global__ __launch_bounds__(512, 2) void k2_gemm(
    const float* __restrict__ x, const float* __restrict__ wgate,
    const unsigned short* __restrict__ Bt, float* __restrict__ C) {
  extern __shared__ unsigned short As[];   // [2][64][CSTR]
  const int t = threadIdx.x;
  const int rowb = blockIdx.x * 64;
  const int wave = t >> 6, lane = t & 63;
  const int mlane = lane & 15, quad = lane >> 4;

  // ---- staging map: thread -> (row, 32 contiguous k within chunk)
  const int srow = t >> 3;            // 0..63
  const int sk   = (t & 7) * 32;      // chunk-local k base
  const float* xrow = x + (size_t)(rowb + srow) * KDIM + sk;
  const float* wrow = wgate + (size_t)(rowb + srow) * 16;
  const int vsub = (t & 7) >> 1;      // v = c*4 + vsub for chunk c
  const float w0 = wrow[vsub], w1 = wrow[4 + vsub],
              w2 = wrow[8 + vsub], w3 = wrow[12 + vsub];

  unsigned short* myA0 = As + srow * CSTR + sk;

  // ---- prologue: load + write chunk 0 into buf0
  f32x4 xr[8];
  #pragma unroll
  for (int i = 0; i < 8; ++i) xr[i] = *(const f32x4*)(xrow + i * 4);
  {
    #pragma unroll
    for (int s = 0; s < 4; ++s) {
      const f32x4 a = xr[2 * s], b2 = xr[2 * s + 1];
      u16x8 o;
      o[0] = f2bf(w0 * a[0]);  o[1] = f2bf(w0 * a[1]);
      o[2] = f2bf(w0 * a[2]);  o[3] = f2bf(w0 * a[3]);
      o[4] = f2bf(w0 * b2[0]); o[5] = f2bf(w0 * b2[1]);
      o[6] = f2bf(w0 * b2[2]); o[7] = f2bf(w0 * b2[3]);
      *(u16x8*)(myA0 + s * 8) = o;
    }
  }
  // issue chunk-1 x loads (land during chunk-0 MFMA)
  #pragma unroll
  for (int i = 0; i < 8; ++i) xr[i] = *(const f32x4*)(xrow + 256 + i * 4);

  // ---- B pointers + 2-deep register prefetch
  const int colb = wave * 64;
  const unsigned short* bp[4];
  #pragma unroll
  for (int j = 0; j < 4; ++j)
    bp[j] = Bt + (size_t)(colb + j * 16 + mlane) * KP + quad * 8;
  bf16x8 bv0[4], bv1[4];
  #pragma unroll
  for (int j = 0; j < 4; ++j) {
    bv0[j] = *(const bf16x8*)(bp[j]);
    bv1[j] = *(const bf16x8*)(bp[j] + 32);
    bp[j] += 64;
  }

  __syncthreads();   // buf0 ready

  f32x4 acc[4][4];
  const f32x4 z = {0.f, 0.f, 0.f, 0.f};
  #pragma unroll
  for (int i = 0; i < 4; ++i)
    #pragma unroll
    for (int j = 0; j < 4; ++j) acc[i][j] = z;

  int ktg = 0;
  #pragma unroll 1
  for (int c = 0; c < 5; ++c) {
    const unsigned short* buf = As + (c & 1) * BUFU16;
    const int nkt = (c < 4) ? 8 : 1;
    #pragma unroll 1
    for (int kt = 0; kt < nkt; ++kt) {
      bf16x8 bnext[4];
      if (ktg < 31) {
        #pragma unroll
        for (int j = 0; j < 4; ++j) { bnext[j] = *(const bf16x8*)bp[j]; bp[j] += 32; }
      }
      bf16x8 av[4];
      #pragma unroll
      for (int i = 0; i < 4; ++i)
        av[i] = *(const bf16x8*)(buf + (i * 16 + mlane) * CSTR + kt * 32 + quad * 8);
      #pragma unroll
      for (int i = 0; i < 4; ++i)
        #pragma unroll
        for (int j = 0; j < 4; ++j)
          acc[i][j] = __builtin_amdgcn_mfma_f32_16x16x32_bf16(av[i], bv0[j], acc[i][j], 0, 0, 0);
      #pragma unroll
      for (int j = 0; j < 4; ++j) { bv0[j] = bv1[j]; bv1[j] = bnext[j]; }
      ++ktg;
    }
    if (c < 3) {
      // write chunk c+1 (already in xr) into buf[(c+1)&1]
      unsigned short* dst = As + ((c + 1) & 1) * BUFU16 + srow * CSTR + sk;
      const float ws = (c == 0) ? w1 : (c == 1) ? w2 : w3;
      #pragma unroll
      for (int s = 0; s < 4; ++s) {
        const f32x4 a = xr[2 * s], b2 = xr[2 * s + 1];
        u16x8 o;
        o[0] = f2bf(ws * a[0]);  o[1] = f2bf(ws * a[1]);
        o[2] = f2bf(ws * a[2]);  o[3] = f2bf(ws * a[3]);
        o[4] = f2bf(ws * b2[0]); o[5] = f2bf(ws * b2[1]);
        o[6] = f2bf(ws * b2[2]); o[7] = f2bf(ws * b2[3]);
        *(u16x8*)(dst + s * 8) = o;
      }
      if (c < 2) {   // issue loads for chunk c+2
        #pragma unroll
        for (int i = 0; i < 8; ++i)
          xr[i] = *(const f32x4*)(xrow + (c + 2) * 256 + i * 4);
      }
      __syncthreads();
    } else if (c == 3) {
      // tail chunk (k 1024..1055): A' = [w row bf16 ; zeros] into buf0
      const int j4 = (t & 7) * 4;   // 0..28
      u16x4 o;
      if (j4 < 16) {
        const f32x4 wv = *(const f32x4*)(wgate + (size_t)(rowb + srow) * 16 + j4);
        o[0] = f2bf(wv[0]); o[1] = f2bf(wv[1]); o[2] = f2bf(wv[2]); o[3] = f2bf(wv[3]);
      } else {
        o[0] = 0; o[1] = 0; o[2] = 0; o[3] = 0;
      }
      *(u16x4*)(As + srow * CSTR + j4) = o;
      __syncthreads();
    }
  }

  // ---- epilogue: C/D layout col=lane&15, row=quad*4+reg  [m89/m91]
  #pragma unroll
  for (int i = 0; i < 4; ++i)
    #pragma unroll
    for (int j = 0; j < 4; ++j)
      #pragma unroll
      for (int r = 0; r < 4; ++r) {
        const size_t row = (size_t)rowb + i * 16 + quad * 4 + r;
        const int col = colb + j * 16 + mlane;
        __builtin_nontemporal_store(acc[i][j][r], &C[row * HDIM + col]);
      }
}

// ---------------------------------------------------------------------------
extern "C" void kernel_launch(void* const* d_in, const int* in_sizes, int n_in,
                              void* d_out, int out_size, void* d_ws, size_t ws_size,
                              hipStream_t stream) {
  const float* x    = (const float*)d_in[0];   // [B, V, S] = [16384][1024] flat
  const float* W    = (const float*)d_in[1];   // [V, S, H] = [1024][512] flat
  const float* bias = (const float*)d_in[2];   // [V, H]
  const float* Wsel = (const float*)d_in[3];   // [H, V]
  const float* bsel = (const float*)d_in[4];   // [V]
  float* out = (float*)d_out;                  // [B, H] fp32

  char* ws = (char*)d_ws;
  unsigned short* Bt     = (unsigned short*)(ws);            // 512*1056*2 = 1,081,344 B
  unsigned short* WcombT = (unsigned short*)(ws + 1081344);  // 16*1024*2  =    32,768 B
  float*          bcomb  = (float*)(ws + 1114112);           // 16*4 (padded to 256)
  float*          wgate  = (float*)(ws + 1114368);           // 16384*16*4 = 1,048,576 B

  static int lds_set = 0;
  if (!lds_set) {
    hipFuncSetAttribute((const void*)k1_gate,
                        hipFuncAttributeMaxDynamicSharedMemorySize, G_LDS);
    hipFuncSetAttribute((const void*)k2_gemm,
                        hipFuncAttributeMaxDynamicSharedMemorySize, GEMM_LDS);
    lds_set = 1;
  }

  k0_prep<<<323, 256, 0, stream>>>(W, bias, Wsel, bsel, Bt, WcombT, bcomb);
  k1_gate<<<512, 512, G_LDS, stream>>>(x, WcombT, bcomb, wgate);
  k2_gemm<<<256, 512, GEMM_LDS, stream>>>(x, wgate, Bt, out);
}

// Round 3
// 158.419 us; speedup vs baseline: 1.0272x; 1.0168x over previous
//
#include <hip/hip_runtime.h>
#include <hip/hip_bf16.h>
#include <stdint.h>

// Shapes (fixed by the problem)
#define B_ROWS 16384
#define VDIM   16
#define SDIM   64
#define HDIM   512
#define KDIM   1024   // V*S
#define KP     1056   // KDIM + 16 bias cols + 16 zero pad

// ---- k1_gate LDS layout (M32 tile)
#define ASTR     1064                 // LDS x-row stride in u16 (1056+8 pad)
#define G_PLOG   68096                // 32*1064*2
#define G_LDS    (68096 + 8704)       // + plog [8][16][17] f32 = 76,800 B -> 2 blk/CU

// ---- k2_gemm LDS layout: double-buffered A-chunk [64][296] bf16
#define CSTR     296                  // 256 + 40 pad
#define BUFU16   (64 * CSTR)          // 18,944 u16 per buffer
#define GEMM_LDS (2 * BUFU16 * 2)     // 75,776 B

using bf16x8 = __attribute__((ext_vector_type(8))) __bf16;
using u16x8  = __attribute__((ext_vector_type(8))) unsigned short;
using u16x4  = __attribute__((ext_vector_type(4))) unsigned short;
using f32x4  = __attribute__((ext_vector_type(4))) float;

__device__ __forceinline__ unsigned short f2bf(float f) {
  unsigned int u = __builtin_bit_cast(unsigned int, f);
  u = (u + 0x7FFFu + ((u >> 16) & 1u)) >> 16;   // RNE
  return (unsigned short)u;
}
__device__ __forceinline__ float bf2f(unsigned short s) {
  return __builtin_bit_cast(float, (unsigned int)s << 16);
}

// ---------------------------------------------------------------------------
// K0 (merged):
//   blocks [0,66):   Bt = [W_cat ; bias ; 0]^T bf16 [HDIM][KP] via LDS-transpose
//   blocks [66,322): WcombT rows; block 322: bcomb.
__global__ __launch_bounds__(256) void k0_prep(
    const float* __restrict__ W, const float* __restrict__ bias,
    const float* __restrict__ Wsel, const float* __restrict__ bsel,
    unsigned short* __restrict__ Bt, unsigned short* __restrict__ WcombT,
    float* __restrict__ bcomb) {
  __shared__ float bm[HDIM];
  __shared__ float part[16][17];
  __shared__ unsigned short tile[32][264];
  const int t = threadIdx.x;
  if (blockIdx.x < 66) {
    const int k0 = (blockIdx.x >> 1) * 32;          // 0..1024 step 32
    const int n  = ((blockIdx.x & 1) << 8) + t;     // 0..511
    #pragma unroll 8
    for (int kk = 0; kk < 32; ++kk) {
      const int k = k0 + kk;
      float val;
      if (k < KDIM)            val = W[(size_t)k * HDIM + n];
      else if (k < KDIM + 16)  val = bias[(size_t)(k - KDIM) * HDIM + n];
      else                     val = 0.f;
      tile[kk][t] = f2bf(val);
    }
    __syncthreads();
    unsigned short* dst = Bt + (size_t)n * KP + k0;
    #pragma unroll
    for (int seg = 0; seg < 4; ++seg) {
      unsigned short o[8];
      #pragma unroll
      for (int jj = 0; jj < 8; ++jj) o[jj] = tile[seg * 8 + jj][t];
      *(u16x8*)(dst + seg * 8) = *(const u16x8*)o;
    }
    return;
  }
  const int bid = blockIdx.x - 66;     // 0..256
  if (bid < 256) {
    const int wave = t >> 6, lane = t & 63;
    const int k = bid * 4 + wave;
    const float* wr = W + (size_t)k * HDIM;
    float s[16];
    #pragma unroll
    for (int v = 0; v < 16; ++v) s[v] = 0.f;
    #pragma unroll
    for (int j = 0; j < 8; ++j) {
      const int h = lane + 64 * j;
      const float a = wr[h];
      const float4* wl = (const float4*)(Wsel + h * 16);
      const float4 q0 = wl[0], q1 = wl[1], q2 = wl[2], q3 = wl[3];
      s[0]  = fmaf(a, q0.x, s[0]);  s[1]  = fmaf(a, q0.y, s[1]);
      s[2]  = fmaf(a, q0.z, s[2]);  s[3]  = fmaf(a, q0.w, s[3]);
      s[4]  = fmaf(a, q1.x, s[4]);  s[5]  = fmaf(a, q1.y, s[5]);
      s[6]  = fmaf(a, q1.z, s[6]);  s[7]  = fmaf(a, q1.w, s[7]);
      s[8]  = fmaf(a, q2.x, s[8]);  s[9]  = fmaf(a, q2.y, s[9]);
      s[10] = fmaf(a, q2.z, s[10]); s[11] = fmaf(a, q2.w, s[11]);
      s[12] = fmaf(a, q3.x, s[12]); s[13] = fmaf(a, q3.y, s[13]);
      s[14] = fmaf(a, q3.z, s[14]); s[15] = fmaf(a, q3.w, s[15]);
    }
    #pragma unroll
    for (int off = 32; off > 0; off >>= 1) {
      #pragma unroll
      for (int v = 0; v < 16; ++v) s[v] += __shfl_xor(s[v], off, 64);
    }
    float mine = 0.f;
    #pragma unroll
    for (int v = 0; v < 16; ++v) mine = (lane == v) ? s[v] : mine;
    if (lane < 16) WcombT[lane * KDIM + k] = f2bf(mine * (1.f / 16.f));
  } else {
    for (int h = t; h < HDIM; h += 256) {
      float s = 0.f;
      #pragma unroll
      for (int v = 0; v < VDIM; ++v) s += bias[v * HDIM + h];
      bm[h] = s * (1.f / 16.f);
    }
    __syncthreads();
    int v = t & 15, sl = t >> 4;
    float s = 0.f;
    for (int h = sl * 32; h < sl * 32 + 32; ++h) s = fmaf(bm[h], Wsel[h * VDIM + v], s);
    part[sl][v] = s;
    __syncthreads();
    if (t < 16) {
      float s2 = bsel[t];
      #pragma unroll
      for (int i = 0; i < 16; ++i) s2 += part[i][t];
      bcomb[t] = s2;
    }
  }
}

// ---------------------------------------------------------------------------
// K1: gate only. M32 tile, grid 512, 2 blocks/CU. Stage bf16(x) -> LDS,
// logits via MFMA vs WcombT, softmax, write w[B][16] fp32. x loads CACHED
// (k2_gemm re-reads x from L3 right after).
__global__ __launch_bounds__(512, 4) void k1_gate(
    const float* __restrict__ x, const unsigned short* __restrict__ WcombT,
    const float* __restrict__ bcomb, float* __restrict__ wgate) {
  extern __shared__ unsigned short As[];          // [32][ASTR] bf16
  float* plog = (float*)((char*)As + G_PLOG);     // [8][16][17]

  const int t = threadIdx.x;
  const int rowb = blockIdx.x * 32;
  const int wave = t >> 6, lane = t & 63;
  const int mlane = lane & 15, quad = lane >> 4;

  // ---- Phase 1: stage bf16(x)
  {
    const int srow = t >> 4;            // 0..31
    const int sc = (t & 15) * 8;        // covers k = sc + i*128
    const float* xr = x + (size_t)(rowb + srow) * KDIM + sc;
    unsigned short* aw = As + srow * ASTR + sc;
    #pragma unroll
    for (int i = 0; i < 8; ++i) {
      const float4 a0 = *(const float4*)(xr + i * 128);
      const float4 a1 = *(const float4*)(xr + i * 128 + 4);
      u16x8 u;
      u[0] = f2bf(a0.x); u[1] = f2bf(a0.y); u[2] = f2bf(a0.z); u[3] = f2bf(a0.w);
      u[4] = f2bf(a1.x); u[5] = f2bf(a1.y); u[6] = f2bf(a1.z); u[7] = f2bf(a1.w);
      *(u16x8*)(aw + i * 128) = u;
    }
  }
  __syncthreads();

  // ---- Phase 2: partial logits. wave w: kh = w>>1 (K-quarter), rg = w&1
  {
    const int kh = wave >> 1, rg = wave & 1;
    const unsigned short* al = As + (rg * 16 + mlane) * ASTR + kh * 256 + quad * 8;
    const unsigned short* bl = WcombT + mlane * KDIM + kh * 256 + quad * 8;
    f32x4 acc = {0.f, 0.f, 0.f, 0.f};
    #pragma unroll
    for (int kt = 0; kt < 8; ++kt) {
      bf16x8 a = *(const bf16x8*)al; al += 32;
      bf16x8 b = *(const bf16x8*)bl; bl += 32;
      acc = __builtin_amdgcn_mfma_f32_16x16x32_bf16(a, b, acc, 0, 0, 0);
    }
    float* pl = plog + ((size_t)((kh * 2 + rg) * 16 + quad * 4) * 17 + mlane);
    #pragma unroll
    for (int r = 0; r < 4; ++r) pl[r * 17] = acc[r];
  }
  __syncthreads();

  // ---- Phase 3: softmax on 32 threads (row = t), write w to global
  if (t < 32) {
    const int rg = t >> 4, rr = t & 15;
    float l[16];
    float mx = -1e30f;
    #pragma unroll
    for (int v = 0; v < 16; ++v) {
      float s = bcomb[v];
      #pragma unroll
      for (int kq = 0; kq < 4; ++kq)
        s += plog[((size_t)((kq * 2 + rg) * 16 + rr)) * 17 + v];
      l[v] = s;
      mx = fmaxf(mx, s);
    }
    float s = 0.f;
    #pragma unroll
    for (int v = 0; v < 16; ++v) { l[v] = __expf(l[v] - mx); s += l[v]; }
    const float inv = 1.f / s;
    float* wo = wgate + (size_t)(rowb + t) * 16;
    #pragma unroll
    for (int q = 0; q < 4; ++q) {
      f32x4 o = {l[4*q] * inv, l[4*q+1] * inv, l[4*q+2] * inv, l[4*q+3] * inv};
      *(f32x4*)(wo + 4 * q) = o;
    }
  }
}

// ---------------------------------------------------------------------------
// K2: chunked double-buffered GEMM. M64 x N512, grid 256 = 1 block/CU.
// Restructured vs R2:
//  - staging ds_write moved to TOP of each chunk (dest buffer dead since the
//    previous barrier) -> off the inter-chunk critical path, 8 K-steps slack
//  - B register prefetch deepened 2 -> 4 (slot = kt&3, static after unroll)
//  - chunk loop fully unrolled: all guards/bases/w-selects compile-time
__global__ __launch_bounds__(512, 2) void k2_gemm(
    const float* __restrict__ x, const float* __restrict__ wgate,
    const unsigned short* __restrict__ Bt, float* __restrict__ C) {
  extern __shared__ unsigned short As[];   // [2][64][CSTR]
  const int t = threadIdx.x;
  const int rowb = blockIdx.x * 64;
  const int wave = t >> 6, lane = t & 63;
  const int mlane = lane & 15, quad = lane >> 4;

  // ---- staging map: thread -> (row, 32 contiguous k within chunk)
  const int srow = t >> 3;            // 0..63
  const int sk   = (t & 7) * 32;      // chunk-local k base
  const float* xrow = x + (size_t)(rowb + srow) * KDIM + sk;
  const float* wrow = wgate + (size_t)(rowb + srow) * 16;
  const int vsub = (t & 7) >> 1;      // v = c*4 + vsub for chunk c
  const float w0 = wrow[vsub], w1 = wrow[4 + vsub],
              w2 = wrow[8 + vsub], w3 = wrow[12 + vsub];

  // ---- prologue: load + write chunk 0 into buf0
  f32x4 xr[8];
  #pragma unroll
  for (int i = 0; i < 8; ++i) xr[i] = *(const f32x4*)(xrow + i * 4);
  {
    unsigned short* dst = As + srow * CSTR + sk;
    #pragma unroll
    for (int s = 0; s < 4; ++s) {
      const f32x4 a = xr[2 * s], b2 = xr[2 * s + 1];
      u16x8 o;
      o[0] = f2bf(w0 * a[0]);  o[1] = f2bf(w0 * a[1]);
      o[2] = f2bf(w0 * a[2]);  o[3] = f2bf(w0 * a[3]);
      o[4] = f2bf(w0 * b2[0]); o[5] = f2bf(w0 * b2[1]);
      o[6] = f2bf(w0 * b2[2]); o[7] = f2bf(w0 * b2[3]);
      *(u16x8*)(dst + s * 8) = o;
    }
  }
  // issue chunk-1 x loads (land during chunk-0 MFMA)
  #pragma unroll
  for (int i = 0; i < 8; ++i) xr[i] = *(const f32x4*)(xrow + 256 + i * 4);

  // ---- B pointers + 4-deep register prefetch (steps 0..3)
  const int colb = wave * 64;
  const unsigned short* bp[4];
  #pragma unroll
  for (int j = 0; j < 4; ++j)
    bp[j] = Bt + (size_t)(colb + j * 16 + mlane) * KP + quad * 8;
  bf16x8 bvs[4][4];
  #pragma unroll
  for (int d = 0; d < 4; ++d)
    #pragma unroll
    for (int j = 0; j < 4; ++j)
      bvs[d][j] = *(const bf16x8*)(bp[j] + d * 32);
  #pragma unroll
  for (int j = 0; j < 4; ++j) bp[j] += 128;   // bp -> step 4

  __syncthreads();   // buf0 ready

  f32x4 acc[4][4];
  const f32x4 z = {0.f, 0.f, 0.f, 0.f};
  #pragma unroll
  for (int i = 0; i < 4; ++i)
    #pragma unroll
    for (int j = 0; j < 4; ++j) acc[i][j] = z;

  // ---- 4 main chunks, fully unrolled. Chunk c reads buf[c&1]; its top
  // writes buf[(c+1)&1] (dead since previous barrier).
  #pragma unroll
  for (int c = 0; c < 4; ++c) {
    // top-of-chunk staging writes
    if (c < 3) {
      const float ws = (c == 0) ? w1 : (c == 1) ? w2 : w3;
      unsigned short* dst = As + ((c + 1) & 1) * BUFU16 + srow * CSTR + sk;
      #pragma unroll
      for (int s = 0; s < 4; ++s) {
        const f32x4 a = xr[2 * s], b2 = xr[2 * s + 1];
        u16x8 o;
        o[0] = f2bf(ws * a[0]);  o[1] = f2bf(ws * a[1]);
        o[2] = f2bf(ws * a[2]);  o[3] = f2bf(ws * a[3]);
        o[4] = f2bf(ws * b2[0]); o[5] = f2bf(ws * b2[1]);
        o[6] = f2bf(ws * b2[2]); o[7] = f2bf(ws * b2[3]);
        *(u16x8*)(dst + s * 8) = o;
      }
      if (c < 2) {   // issue loads for chunk c+2
        #pragma unroll
        for (int i = 0; i < 8; ++i)
          xr[i] = *(const f32x4*)(xrow + (c + 2) * 256 + i * 4);
      }
    } else {
      // tail chunk (k 1024..1055) into buf0: A' = [w row bf16 ; zeros]
      const int j4 = (t & 7) * 4;   // 0..28
      u16x4 o;
      if (j4 < 16) {
        const f32x4 wv = *(const f32x4*)(wgate + (size_t)(rowb + srow) * 16 + j4);
        o[0] = f2bf(wv[0]); o[1] = f2bf(wv[1]); o[2] = f2bf(wv[2]); o[3] = f2bf(wv[3]);
      } else {
        o[0] = 0; o[1] = 0; o[2] = 0; o[3] = 0;
      }
      *(u16x4*)(As + srow * CSTR + j4) = o;
    }

    // 8 K-steps on buf[c&1]
    const unsigned short* buf = As + (c & 1) * BUFU16;
    #pragma unroll
    for (int kt = 0; kt < 8; ++kt) {
      const int ktg = c * 8 + kt;         // compile-time
      bf16x8 cur[4];
      #pragma unroll
      for (int j = 0; j < 4; ++j) cur[j] = bvs[kt & 3][j];
      if (ktg + 4 <= 32) {                // steps 0..32 exist
        #pragma unroll
        for (int j = 0; j < 4; ++j) { bvs[kt & 3][j] = *(const bf16x8*)bp[j]; bp[j] += 32; }
      }
      bf16x8 av[4];
      #pragma unroll
      for (int i = 0; i < 4; ++i)
        av[i] = *(const bf16x8*)(buf + (i * 16 + mlane) * CSTR + kt * 32 + quad * 8);
      #pragma unroll
      for (int i = 0; i < 4; ++i)
        #pragma unroll
        for (int j = 0; j < 4; ++j)
          acc[i][j] = __builtin_amdgcn_mfma_f32_16x16x32_bf16(av[i], cur[j], acc[i][j], 0, 0, 0);
    }
    __syncthreads();
  }

  // ---- tail K-step: ktg = 32, slot 0 holds B step 32, A from buf0
  {
    bf16x8 av[4];
    #pragma unroll
    for (int i = 0; i < 4; ++i)
      av[i] = *(const bf16x8*)(As + (i * 16 + mlane) * CSTR + quad * 8);
    #pragma unroll
    for (int i = 0; i < 4; ++i)
      #pragma unroll
      for (int j = 0; j < 4; ++j)
        acc[i][j] = __builtin_amdgcn_mfma_f32_16x16x32_bf16(av[i], bvs[0][j], acc[i][j], 0, 0, 0);
  }

  // ---- epilogue: C/D layout col=lane&15, row=quad*4+reg  [m89/m91]
  #pragma unroll
  for (int i = 0; i < 4; ++i)
    #pragma unroll
    for (int j = 0; j < 4; ++j)
      #pragma unroll
      for (int r = 0; r < 4; ++r) {
        const size_t row = (size_t)rowb + i * 16 + quad * 4 + r;
        const int col = colb + j * 16 + mlane;
        __builtin_nontemporal_store(acc[i][j][r], &C[row * HDIM + col]);
      }
}

// ---------------------------------------------------------------------------
extern "C" void kernel_launch(void* const* d_in, const int* in_sizes, int n_in,
                              void* d_out, int out_size, void* d_ws, size_t ws_size,
                              hipStream_t stream) {
  const float* x    = (const float*)d_in[0];   // [B, V, S] = [16384][1024] flat
  const float* W    = (const float*)d_in[1];   // [V, S, H] = [1024][512] flat
  const float* bias = (const float*)d_in[2];   // [V, H]
  const float* Wsel = (const float*)d_in[3];   // [H, V]
  const float* bsel = (const float*)d_in[4];   // [V]
  float* out = (float*)d_out;                  // [B, H] fp32

  char* ws = (char*)d_ws;
  unsigned short* Bt     = (unsigned short*)(ws);            // 512*1056*2 = 1,081,344 B
  unsigned short* WcombT = (unsigned short*)(ws + 1081344);  // 16*1024*2  =    32,768 B
  float*          bcomb  = (float*)(ws + 1114112);           // 16*4 (padded to 256)
  float*          wgate  = (float*)(ws + 1114368);           // 16384*16*4 = 1,048,576 B

  static int lds_set = 0;
  if (!lds_set) {
    hipFuncSetAttribute((const void*)k1_gate,
                        hipFuncAttributeMaxDynamicSharedMemorySize, G_LDS);
    hipFuncSetAttribute((const void*)k2_gemm,
                        hipFuncAttributeMaxDynamicSharedMemorySize, GEMM_LDS);
    lds_set = 1;
  }

  k0_prep<<<323, 256, 0, stream>>>(W, bias, Wsel, bsel, Bt, WcombT, bcomb);
  k1_gate<<<512, 512, G_LDS, stream>>>(x, WcombT, bcomb, wgate);
  k2_gemm<<<256, 512, GEMM_LDS, stream>>>(x, wgate, Bt, out);
}